// Round 7
// baseline (84835.504 us; speedup 1.0000x reference)
//
#include <hip/hip_runtime.h>
#include <cstdint>
#include <cstddef>

// ---------------------------------------------------------------------------
// Tacotron2-style decoder. Persistent kernel (256 blocks x 256 threads,
// 1 block/CU) with LSTM weights in VGPRs/AGPRs (persistent-RNN), fence-free
// LLC grid barrier, and WRITE-ONCE per-step state buffers so staging loads
// are plain (L2-cached, 16x reuse per XCD) instead of sc1 (HBM).
// Falls back to the round-6 sc1 ping-pong path if ws_size is insufficient.
// ---------------------------------------------------------------------------

#define BB   32
#define SS   512
#define EMBD 256
#define MELD 80
#define PRED 256
#define RNND 1024
#define ATTD 128
#define TT   400
#define NBLK 256
#define CTXS (BB * EMBD)     // 8192 floats per ctx slot
#define HS   (BB * RNND)     // 32768 floats per h/c slot

// ------------------------------- threefry ---------------------------------
__device__ __forceinline__ void tf_block(uint32_t k0, uint32_t k1,
                                         uint32_t x0, uint32_t x1,
                                         uint32_t& o0, uint32_t& o1) {
  uint32_t ks2 = k0 ^ k1 ^ 0x1BD11BDAu;
  x0 += k0; x1 += k1;
#define TFR(r) { x0 += x1; x1 = (x1 << (r)) | (x1 >> (32 - (r))); x1 ^= x0; }
  TFR(13) TFR(15) TFR(26) TFR(6)
  x0 += k1;  x1 += ks2 + 1u;
  TFR(17) TFR(29) TFR(16) TFR(24)
  x0 += ks2; x1 += k0 + 2u;
  TFR(13) TFR(15) TFR(26) TFR(6)
  x0 += k0;  x1 += k1 + 3u;
  TFR(17) TFR(29) TFR(16) TFR(24)
  x0 += k1;  x1 += ks2 + 4u;
  TFR(13) TFR(15) TFR(26) TFR(6)
  x0 += ks2; x1 += k0 + 5u;
#undef TFR
  o0 = x0; o1 = x1;
}

__device__ __forceinline__ void subkey(int t, int j, uint32_t& k0, uint32_t& k1) {
  uint32_t a, b;
  tf_block(0u, 42u, 0u, (uint32_t)t, a, b);   // fold_in
  tf_block(a, b, 0u, (uint32_t)j, k0, k1);    // partitionable split
}

__device__ __forceinline__ bool keep_draw(uint32_t k0, uint32_t k1,
                                          uint32_t idx, float pkeep) {
  uint32_t o0, o1;
  tf_block(k0, k1, 0u, idx, o0, o1);
  uint32_t bits = o0 ^ o1;
  float u = __uint_as_float((bits >> 9) | 0x3f800000u) - 1.0f;
  return u < pkeep;
}

__device__ __forceinline__ float sigm(float x) { return 1.0f / (1.0f + expf(-x)); }

// ----------------------- LLC-coherent (sc0 sc1) ops ------------------------
__device__ __forceinline__ void llc_load1x2(const float* p0, const float* p1,
                                            float& v0, float& v1) {
  asm volatile(
      "global_load_dword %0, %2, off sc0 sc1\n"
      "global_load_dword %1, %3, off sc0 sc1\n"
      "s_waitcnt vmcnt(0)"
      : "=&v"(v0), "=&v"(v1) : "v"(p0), "v"(p1) : "memory");
}
__device__ __forceinline__ float4 llc_load4(const float4* p) {
  float4 v;
  asm volatile("global_load_dwordx4 %0, %1, off sc0 sc1\ns_waitcnt vmcnt(0)"
               : "=v"(v) : "v"(p) : "memory");
  return v;
}
__device__ __forceinline__ void llc_store1(float* p, float v) {
  asm volatile("global_store_dword %0, %1, off sc0 sc1" :: "v"(p), "v"(v) : "memory");
}
__device__ __forceinline__ uint32_t llc_loadu(const uint32_t* p) {
  uint32_t v;
  asm volatile("global_load_dword %0, %1, off sc0 sc1\ns_waitcnt vmcnt(0)"
               : "=v"(v) : "v"(p) : "memory");
  return v;
}
__device__ __forceinline__ void llc_storeu(uint32_t* p, uint32_t v) {
  asm volatile("global_store_dword %0, %1, off sc0 sc1" :: "v"(p), "v"(v) : "memory");
}
// issue one f4 load WITHOUT waiting; SC=true -> sc0 sc1 (LLC), false -> cached
template<bool SC>
__device__ __forceinline__ void issue_f4(const float4* p, float4& v) {
  if constexpr (SC)
    asm volatile("global_load_dwordx4 %0, %1, off sc0 sc1"
                 : "=v"(v) : "v"(p) : "memory");
  else
    asm volatile("global_load_dwordx4 %0, %1, off"
                 : "=v"(v) : "v"(p) : "memory");
}
__device__ __forceinline__ void waitv0() {
  asm volatile("s_waitcnt vmcnt(0)" ::: "memory");
}

// --------------------- fence-free grid barrier (flags) ---------------------
__device__ __forceinline__ void gsync(uint32_t* flags, uint32_t* gen, uint32_t& lgen) {
  asm volatile("s_waitcnt vmcnt(0)" ::: "memory");
  __syncthreads();
  lgen += 1u;
  if (blockIdx.x == 0) {
    if (threadIdx.x > 0) {
      uint32_t g;
      do {
        g = llc_loadu(&flags[threadIdx.x]);
        if (g >= lgen) break;
        __builtin_amdgcn_s_sleep(1);
      } while (true);
    }
    __syncthreads();
    if (threadIdx.x == 0) llc_storeu(gen, lgen);
  } else {
    if (threadIdx.x == 0) {
      llc_storeu(&flags[blockIdx.x], lgen);
      uint32_t g;
      do {
        g = llc_loadu(gen);
        if (g >= lgen) break;
        __builtin_amdgcn_s_sleep(2);
      } while (true);
    }
  }
  __syncthreads();
}

// ------------------------------ init ---------------------------------------
__global__ void init_kernel(float* statebase, int nstate) {
  int i = blockIdx.x * blockDim.x + threadIdx.x;
  if (i < nstate) statebase[i] = 0.0f;
}

// --------------------------- prenet (all t) --------------------------------
__global__ __launch_bounds__(256) void prenet_kernel(
    const float* __restrict__ tmels, const float* __restrict__ W1,
    const float* __restrict__ b1, const float* __restrict__ W2,
    const float* __restrict__ b2, float* __restrict__ P_all) {
  __shared__ float melsh[MELD];
  __shared__ float h1sh[PRED];
  int blk = blockIdx.x, tid = threadIdx.x;
  int t = blk >> 5, b = blk & 31;
  if (tid < MELD)
    melsh[tid] = (t == 0) ? 0.0f : tmels[((size_t)b * TT + (t - 1)) * MELD + tid];
  __syncthreads();
  uint32_t k10, k11, k20, k21;
  subkey(t, 0, k10, k11);
  subkey(t, 1, k20, k21);
  {
    const float* wr = W1 + (size_t)tid * MELD;
    float acc = b1[tid];
    for (int m = 0; m < MELD; ++m) acc += melsh[m] * wr[m];
    acc = fmaxf(acc, 0.0f);
    bool kp = keep_draw(k10, k11, (uint32_t)(b * PRED + tid), 0.5f);
    h1sh[tid] = kp ? (acc / 0.5f) : 0.0f;
  }
  __syncthreads();
  {
    const float* wr = W2 + (size_t)tid * PRED;
    float acc = b2[tid];
    for (int k = 0; k < PRED; ++k) acc += h1sh[k] * wr[k];
    acc = fmaxf(acc, 0.0f);
    bool kp = keep_draw(k20, k21, (uint32_t)(b * PRED + tid), 0.5f);
    P_all[((size_t)t * BB + b) * PRED + tid] = kp ? (acc / 0.5f) : 0.0f;
  }
}

// ------------------------------ mem_proj -----------------------------------
__global__ __launch_bounds__(128) void memproj_kernel(
    const float* __restrict__ emb, const float* __restrict__ Wmem,
    float* __restrict__ mp) {
  __shared__ float esh[EMBD];
  int blk = blockIdx.x, tid = threadIdx.x;   // blk = b*S + s
  const float* er = emb + (size_t)blk * EMBD;
  esh[tid] = er[tid];
  esh[tid + 128] = er[tid + 128];
  __syncthreads();
  const float4* wr = (const float4*)(Wmem + (size_t)tid * EMBD);
  const float4* xr = (const float4*)esh;
  float acc = 0.0f;
  for (int k4 = 0; k4 < EMBD / 4; ++k4) {
    float4 w = wr[k4], x = xr[k4];
    acc += w.x * x.x + w.y * x.y + w.z * x.z + w.w * x.w;
  }
  mp[(size_t)blk * ATTD + tid] = acc;
}

// ------------------------------- params ------------------------------------
struct DecParams {
  const float *emb, *tmels;
  const float *Wih_pre, *Whh_pre, *bih_pre, *bhh_pre;
  const float *Wq, *conv_w, *Wloc, *vvec;
  const float *Wih_post, *Whh_post, *bih_post, *bhh_post;
  const float *Wmel, *bmel, *Wstop, *bstop;
  float *out;
  float *memproj, *P_all;
  // fallback ping-pong
  float *Apre0, *Apre1, *Bpre0, *Bpre1;
  float *Apost0, *Apost1, *Bpost0, *Bpost1;
  float *ctx0, *ctx1;
  // shared small state (both modes)
  float *aw0, *aw1, *asum0, *asum1;
  float *energ;
  // fresh per-step buffers (mode 1)
  float *ctx_all, *Apre_all, *Bpre_all, *Apost_all;
  float *ctx_init, *Apre_init, *Apost_init;
  uint32_t *flags;
  int mode;
};

// ---------------- VGPR-resident weight load (one-time) ---------------------
template<int NJ, int SL, int KIH>
__device__ __forceinline__ void load_weights(
    float4 (&w)[4][18], float (&bs)[4], int hb, int tid,
    const float* __restrict__ Wih, const float* __restrict__ Whh,
    const float* __restrict__ bih, const float* __restrict__ bhh) {
  const int r = tid >> 5, s = tid & 31;
#pragma unroll
  for (int g = 0; g < 4; ++g) {
    int gcol = g * RNND + hb + r;
    bs[g] = bih[gcol] + bhh[gcol];
#pragma unroll
    for (int j4 = 0; j4 < NJ; ++j4) {
      float4 v4;
      { int k = s * SL + j4 * 4 + 0;
        v4.x = (k < KIH) ? Wih[(size_t)gcol * KIH + k] : Whh[(size_t)gcol * RNND + (k - KIH)]; }
      { int k = s * SL + j4 * 4 + 1;
        v4.y = (k < KIH) ? Wih[(size_t)gcol * KIH + k] : Whh[(size_t)gcol * RNND + (k - KIH)]; }
      { int k = s * SL + j4 * 4 + 2;
        v4.z = (k < KIH) ? Wih[(size_t)gcol * KIH + k] : Whh[(size_t)gcol * RNND + (k - KIH)]; }
      { int k = s * SL + j4 * 4 + 3;
        v4.w = (k < KIH) ? Wih[(size_t)gcol * KIH + k] : Whh[(size_t)gcol * RNND + (k - KIH)]; }
      w[g][j4] = v4;
    }
  }
}

// ------------------- phase A: one LSTM cell, weights in regs ----------------
template<bool SC, int NJ, int SLP, int NL, int F4B, int L0, int S0>
__device__ __forceinline__ void lstm_phaseA(
    int tid, int hb, int tdraw, int jdraw,
    const float4 (&w)[4][18], const float (&bs)[4], float& c_state,
    const float* __restrict__ src0, const float* __restrict__ ctxp,
    const float* __restrict__ srcR,
    float* Aw, float* Bw, float* xs, float* gates) {
  const int r = tid >> 5;
  const int s = tid & 31;
  float4 rg[9];

  auto issue = [&](int c) {
#pragma unroll
    for (int i = 0; i < NL; ++i) {
      int flat = i * 256 + tid;
      int bl = flat / F4B;
      int k4 = flat - bl * F4B;
      int k = k4 * 4;
      int bg = c * 4 + bl;
      const float* sp;
      if (k < L0)            sp = src0 + (size_t)bg * S0 + k;
      else if (k < L0 + 256) sp = ctxp + bg * 256 + (k - L0);
      else                   sp = srcR + (size_t)bg * 1024 + (k - L0 - 256);
      issue_f4<SC>((const float4*)sp, rg[i]);
    }
  };

  issue(0);
  for (int c = 0; c < 8; ++c) {
    __syncthreads();
    waitv0();
    __builtin_amdgcn_sched_barrier(0);
#pragma unroll
    for (int i = 0; i < NL; ++i) {
      int flat = i * 256 + tid;
      int bl = flat / F4B;
      int k4 = flat - bl * F4B;
      int slice = k4 / NJ;
      int j4 = k4 - slice * NJ;
      *(float4*)(xs + (bl * 32 + slice) * SLP + j4 * 4) = rg[i];
    }
    __syncthreads();
    if (c < 7) issue(c + 1);
#pragma unroll
    for (int bl = 0; bl < 4; ++bl) {
      const float4* xb = (const float4*)(xs + (bl * 32 + s) * SLP);
      float a0 = 0.f, a1 = 0.f, a2 = 0.f, a3 = 0.f;
#pragma unroll
      for (int j4 = 0; j4 < NJ; ++j4) {
        float4 x4 = xb[j4];
        a0 += w[0][j4].x * x4.x + w[0][j4].y * x4.y + w[0][j4].z * x4.z + w[0][j4].w * x4.w;
        a1 += w[1][j4].x * x4.x + w[1][j4].y * x4.y + w[1][j4].z * x4.z + w[1][j4].w * x4.w;
        a2 += w[2][j4].x * x4.x + w[2][j4].y * x4.y + w[2][j4].z * x4.z + w[2][j4].w * x4.w;
        a3 += w[3][j4].x * x4.x + w[3][j4].y * x4.y + w[3][j4].z * x4.z + w[3][j4].w * x4.w;
      }
#pragma unroll
      for (int m = 1; m < 32; m <<= 1) {
        a0 += __shfl_xor(a0, m);
        a1 += __shfl_xor(a1, m);
        a2 += __shfl_xor(a2, m);
        a3 += __shfl_xor(a3, m);
      }
      if (s == 0) {
        float4 g4;
        g4.x = a0 + bs[0]; g4.y = a1 + bs[1]; g4.z = a2 + bs[2]; g4.w = a3 + bs[3];
        ((float4*)gates)[(c * 4 + bl) * 8 + r] = g4;
      }
    }
  }
  __syncthreads();
  {
    const int hloc = r, bb = s;
    float4 g4 = ((const float4*)gates)[bb * 8 + hloc];
    uint32_t kk0, kk1;
    subkey(tdraw, jdraw, kk0, kk1);
    float iv = sigm(g4.x), fv = sigm(g4.y), gv = tanhf(g4.z), ov = sigm(g4.w);
    float c_new = fv * c_state + iv * gv;
    c_state = c_new;
    float h_new = ov * tanhf(c_new);
    bool kp = keep_draw(kk0, kk1, (uint32_t)(bb * RNND + hb + hloc), 0.9f);
    llc_store1(Aw + (size_t)bb * RNND + hb + hloc, kp ? (h_new / 0.9f) : 0.0f);
    llc_store1(Bw + (size_t)bb * RNND + hb + hloc, c_new);
  }
}

// ---------------------------------------------------------------------------
__global__ __launch_bounds__(256, 1) void decoder_persistent(DecParams p) {
  __shared__ __align__(16) float smem[11008];   // 44 KB, unioned per phase
  const int blk = blockIdx.x;
  const int tid = threadIdx.x;
  uint32_t* flags = p.flags;
  uint32_t* gen = p.flags + NBLK;
  uint32_t lgen = 0u;
  const int mode = p.mode;

  const bool is1 = (blk < 128);
  const int hb = (is1 ? blk : blk - 128) * 8;

  float4 w[4][18];
  float bs[4];
  if (is1) load_weights<12, 48, 512>(w, bs, hb, tid, p.Wih_pre, p.Whh_pre,
                                     p.bih_pre, p.bhh_pre);
  else     load_weights<18, 72, 1280>(w, bs, hb, tid, p.Wih_post, p.Whh_post,
                                      p.bih_post, p.bhh_post);
  float c_state = 0.0f;

  for (int t = 0; t <= TT; ++t) {
    const int rr = t & 1;
    // -------- per-iter pointers (mode 1: fresh buffers; mode 0: r6 parity) --
    const float *l1_ctx, *l1_srcR, *l2_src0, *l2_ctx, *l2_srcR;
    float *l1_Aw, *l1_Bw, *l2_Aw, *l2_Bw;
    const float *hq, *ctx_out;     // E query source; outproj ctx source
    float *ctxW, *bpostW;
    const float* l1_src0 = p.P_all + (size_t)t * BB * PRED;
    if (mode) {
      l1_ctx  = t ? p.ctx_all  + (size_t)(t - 1) * CTXS : p.ctx_init;
      l1_srcR = t ? p.Apre_all + (size_t)(t - 1) * HS   : p.Apre_init;
      l1_Aw   = p.Apre_all + (size_t)t * HS;
      l1_Bw   = p.Bpre_all + (size_t)t * HS;
      int tau = t - 1;          // lstm2 step
      l2_src0 = p.Bpre_all + (size_t)(tau < 0 ? 0 : tau) * HS;
      l2_ctx  = (tau >= 0) ? p.ctx_all + (size_t)tau * CTXS : p.ctx_init;
      l2_srcR = (tau >= 1) ? p.Apost_all + (size_t)(tau - 1) * HS : p.Apost_init;
      l2_Aw   = p.Apost_all + (size_t)(tau < 0 ? 0 : tau) * HS;
      l2_Bw   = p.Bpost0;
      hq      = p.Bpre_all + (size_t)t * HS;
      ctxW    = p.ctx_all + (size_t)t * CTXS;
      ctx_out = t ? p.ctx_all + (size_t)(t - 1) * CTXS : p.ctx_init;
      bpostW  = p.Bpost0;
    } else {
      l1_ctx  = rr ? p.ctx1 : p.ctx0;
      l1_srcR = rr ? p.Apre1 : p.Apre0;
      l1_Aw   = rr ? p.Apre0 : p.Apre1;
      l1_Bw   = rr ? p.Bpre0 : p.Bpre1;
      l2_src0 = rr ? p.Bpre1 : p.Bpre0;
      l2_ctx  = rr ? p.ctx1 : p.ctx0;
      l2_srcR = rr ? p.Apost0 : p.Apost1;
      l2_Aw   = rr ? p.Apost1 : p.Apost0;
      l2_Bw   = rr ? p.Bpost1 : p.Bpost0;
      hq      = l1_Bw;
      ctxW    = rr ? p.ctx0 : p.ctx1;
      ctx_out = l2_ctx;
      bpostW  = l2_Bw;
    }
    const float* aw_r   = rr ? p.aw1   : p.aw0;
    float*       aw_w   = rr ? p.aw0   : p.aw1;
    const float* asum_r = rr ? p.asum1 : p.asum0;
    float*       asum_w = rr ? p.asum0 : p.asum1;

    // ---------------- phase A: lstm1(t) [blk<128] + lstm2(t-1) -------------
    if (is1) {
      if (t < TT) {
        if (mode)
          lstm_phaseA<false, 12, 53, 6, 384, 256, 256>(
              tid, hb, t, 2, w, bs, c_state, l1_src0, l1_ctx, l1_srcR,
              l1_Aw, l1_Bw, smem, smem + 9920);
        else
          lstm_phaseA<true, 12, 53, 6, 384, 256, 256>(
              tid, hb, t, 2, w, bs, c_state, l1_src0, l1_ctx, l1_srcR,
              l1_Aw, l1_Bw, smem, smem + 9920);
      }
    } else {
      if (t > 0) {
        if (mode)
          lstm_phaseA<false, 18, 77, 9, 576, 1024, 1024>(
              tid, hb, t - 1, 3, w, bs, c_state, l2_src0, l2_ctx, l2_srcR,
              l2_Aw, l2_Bw, smem, smem + 9920);
        else
          lstm_phaseA<true, 18, 77, 9, 576, 1024, 1024>(
              tid, hb, t - 1, 3, w, bs, c_state, l2_src0, l2_ctx, l2_srcR,
              l2_Aw, l2_Bw, smem, smem + 9920);
      }
    }
    gsync(flags, gen, lgen);

    // -------- phase E: q-recompute + conv + energies (256 blocks) ----------
    if (t < TT) {
      float* qsh   = smem;           // 128
      float* vsh   = smem + 128;     // 128
      float* awin  = smem + 256;     // 94 (pad 96)
      float* aswin = smem + 352;     // 94 (pad 96)
      float* wlocs = smem + 448;     // 128*33 = 4224
      float* convs = smem + 4672;    // 32*62 = 1984
      float* locs  = smem + 6656;    // 64*33 = 2112 -> 8768
      float* hsh   = smem + 8960;    // 1024
      float* qpart = smem + 9984;    // 256
      int b = blk >> 3, st = blk & 7, s0 = st * 64;
      {
        float4 hv;
        if (mode) hv = ((const float4*)(hq + (size_t)b * RNND))[tid];
        else      hv = llc_load4(((const float4*)(hq + (size_t)b * RNND)) + tid);
        ((float4*)hsh)[tid] = hv;
      }
      if (tid < ATTD) vsh[tid] = p.vvec[tid];
      if (tid < 94) {
        int sg = s0 - 15 + tid;
        bool ok = (sg >= 0) && (sg < SS);
        float av = 0.0f, sv = 0.0f;
        if (ok) llc_load1x2(&aw_r[b * SS + sg], &asum_r[b * SS + sg], av, sv);
        awin[tid]  = av;
        aswin[tid] = sv;
      }
      for (int idx = tid; idx < ATTD * 32; idx += 256) {
        int a = idx >> 5, c = idx & 31;
        wlocs[a * 33 + c] = p.Wloc[a * 32 + c];
      }
      for (int idx = tid; idx < 32 * 62; idx += 256) convs[idx] = p.conv_w[idx];
      __syncthreads();
      {
        int a = tid & 127, half = tid >> 7;
        const float4* wr = ((const float4*)(p.Wq + (size_t)a * RNND)) + half * 128;
        const float4* xr = ((const float4*)hsh) + half * 128;
        float acc = 0.0f;
        for (int k4 = 0; k4 < 128; ++k4) {
          float4 wv = wr[k4], x = xr[k4];
          acc += wv.x * x.x + wv.y * x.y + wv.z * x.z + wv.w * x.w;
        }
        qpart[half * 128 + a] = acc;
      }
      __syncthreads();
      if (tid < 128) qsh[tid] = qpart[tid] + qpart[128 + tid];
      for (int idx = tid; idx < 64 * 32; idx += 256) {
        int sl = idx & 63, c = idx >> 6;
        const float* cw0 = &convs[c * 62];
        const float* cw1 = &convs[c * 62 + 31];
        float acc = 0.0f;
        for (int k = 0; k < 31; ++k)
          acc += cw0[k] * aswin[sl + k] + cw1[k] * awin[sl + k];
        locs[sl * 33 + c] = acc;
      }
      __syncthreads();
      int sl = tid >> 2, aq = tid & 3, sg = s0 + sl;
      const float* mp = p.memproj + ((size_t)b * SS + sg) * ATTD;
      float acc = 0.0f;
      const float* ls = &locs[sl * 33];
      for (int j = 0; j < 32; ++j) {
        int a = j * 4 + aq;
        const float* wl = &wlocs[a * 33];
        float lp = 0.0f;
#pragma unroll 8
        for (int c = 0; c < 32; ++c) lp += ls[c] * wl[c];
        acc += vsh[a] * tanhf(qsh[a] + mp[a] + lp);
      }
      acc += __shfl_down(acc, 2);
      acc += __shfl_down(acc, 1);
      if (aq == 0) llc_store1(&p.energ[b * SS + sg], acc);
    }
    gsync(flags, gen, lgen);

    // ------- phase C: softmax+context (blk<128) | outproj (128..159) -------
    if (t < TT && blk < 128) {
      float* psh   = smem;           // 512
      float* red   = smem + 512;     // 256
      float (*cpart)[64] = (float (*)[64])(smem + 768);  // 4 x 64
      int b = blk >> 2, ec = blk & 3;
      float e1, e2;
      llc_load1x2(&p.energ[b * SS + tid], &p.energ[b * SS + 256 + tid], e1, e2);
      red[tid] = fmaxf(e1, e2);
      __syncthreads();
      for (int s2 = 128; s2 > 0; s2 >>= 1) {
        if (tid < s2) red[tid] = fmaxf(red[tid], red[tid + s2]);
        __syncthreads();
      }
      float mx = red[0];
      __syncthreads();
      float p1 = expf(e1 - mx), p2 = expf(e2 - mx);
      psh[tid] = p1; psh[tid + 256] = p2;
      red[tid] = p1 + p2;
      __syncthreads();
      for (int s2 = 128; s2 > 0; s2 >>= 1) {
        if (tid < s2) red[tid] += red[tid + s2];
        __syncthreads();
      }
      float inv = 1.0f / red[0];
      int el = tid & 63, sq = tid >> 6;
      int e = ec * 64 + el;
      float acc = 0.0f;
      const float* ebase = p.emb + ((size_t)b * SS) * EMBD + e;
      for (int s2 = sq * 128; s2 < sq * 128 + 128; ++s2)
        acc += psh[s2] * ebase[(size_t)s2 * EMBD];
      cpart[sq][el] = acc;
      __syncthreads();
      if (tid < 64)
        llc_store1(&ctxW[b * EMBD + ec * 64 + tid],
                   (cpart[0][tid] + cpart[1][tid] + cpart[2][tid] + cpart[3][tid]) * inv);
      if (ec == 0) {
        float a1 = p1 * inv, a2 = p2 * inv;
        float s1, s2v;
        llc_load1x2(&asum_r[b * SS + tid], &asum_r[b * SS + 256 + tid], s1, s2v);
        llc_store1(&aw_w[b * SS + tid], a1);
        llc_store1(&aw_w[b * SS + 256 + tid], a2);
        llc_store1(&asum_w[b * SS + tid], s1 + a1);
        llc_store1(&asum_w[b * SS + 256 + tid], s2v + a2);
      }
    } else if (t > 0 && blk >= 128 && blk < 160) {
      float* xall = smem;            // 1024 + 256
      int b = blk - 128;
      int t_prev = t - 1;
      {
        // Bpost is reused every step -> must stay sc1 (no cached copy allowed)
        float4 hv = llc_load4(((const float4*)(bpostW + (size_t)b * RNND)) + tid);
        ((float4*)xall)[tid] = hv;
        if (tid < 64) {
          float4 cv;
          if (mode) cv = ((const float4*)(ctx_out + (size_t)b * EMBD))[tid];
          else      cv = llc_load4(((const float4*)(ctx_out + (size_t)b * EMBD)) + tid);
          ((float4*)(xall + RNND))[tid] = cv;
        }
      }
      __syncthreads();
      int o = tid;
      if (o <= 80) {
        const float* wrow = (o < 80) ? (p.Wmel + (size_t)o * 1280) : p.Wstop;
        const float4* w4 = (const float4*)wrow;
        const float4* x4 = (const float4*)xall;
        float acc = 0.0f;
        for (int k4 = 0; k4 < 320; ++k4) {
          float4 wv = w4[k4], x = x4[k4];
          acc += wv.x * x.x + wv.y * x.y + wv.z * x.z + wv.w * x.w;
        }
        acc += (o < 80) ? p.bmel[o] : p.bstop[0];
        float val = sigm(acc);
        if (o < 80)
          p.out[(size_t)b * (TT * MELD) + (size_t)t_prev * MELD + o] = val;
        else
          p.out[(size_t)BB * TT * MELD + (size_t)b * TT + t_prev] = val;
      }
    }
    gsync(flags, gen, lgen);
  }
}

// ------------------------------- launch ------------------------------------
extern "C" void kernel_launch(void* const* d_in, const int* in_sizes, int n_in,
                              void* d_out, int out_size, void* d_ws, size_t ws_size,
                              hipStream_t stream) {
  DecParams hp;
  hp.emb      = (const float*)d_in[0];
  hp.tmels    = (const float*)d_in[1];
  const float* W1 = (const float*)d_in[2];
  const float* b1 = (const float*)d_in[3];
  const float* W2 = (const float*)d_in[4];
  const float* b2 = (const float*)d_in[5];
  hp.Wih_pre  = (const float*)d_in[6];
  hp.Whh_pre  = (const float*)d_in[7];
  hp.bih_pre  = (const float*)d_in[8];
  hp.bhh_pre  = (const float*)d_in[9];
  hp.Wq       = (const float*)d_in[10];
  const float* Wmem = (const float*)d_in[11];
  hp.conv_w   = (const float*)d_in[12];
  hp.Wloc     = (const float*)d_in[13];
  hp.vvec     = (const float*)d_in[14];
  hp.Wih_post = (const float*)d_in[15];
  hp.Whh_post = (const float*)d_in[16];
  hp.bih_post = (const float*)d_in[17];
  hp.bhh_post = (const float*)d_in[18];
  hp.Wmel     = (const float*)d_in[19];
  hp.bmel     = (const float*)d_in[20];
  hp.Wstop    = (const float*)d_in[21];
  hp.bstop    = (const float*)d_in[22];
  hp.out = (float*)d_out;

  float* w = (float*)d_ws;
  size_t off = 0;
  auto carve = [&](size_t n) {
    float* ptr = w + off;
    off += (n + 63) & ~((size_t)63);
    return ptr;
  };
  hp.memproj = carve((size_t)BB * SS * ATTD);
  hp.P_all   = carve((size_t)TT * BB * PRED);
  size_t state_begin = off;
  hp.Apre0  = carve(HS); hp.Apre1  = carve(HS);
  hp.Bpre0  = carve(HS); hp.Bpre1  = carve(HS);
  hp.Apost0 = carve(HS); hp.Apost1 = carve(HS);
  hp.Bpost0 = carve(HS); hp.Bpost1 = carve(HS);
  hp.ctx0   = carve(CTXS); hp.ctx1 = carve(CTXS);
  hp.aw0    = carve(BB * SS);   hp.aw1    = carve(BB * SS);
  hp.asum0  = carve(BB * SS);   hp.asum1  = carve(BB * SS);
  hp.ctx_init  = carve(CTXS);
  hp.Apre_init = carve(HS);
  hp.Apost_init = carve(HS);
  hp.energ  = carve(BB * SS);
  hp.flags  = (uint32_t*)carve(512);
  size_t state_end = off;
  int nstate = (int)(state_end - state_begin);
  // fresh per-step buffers (mode 1) — 401 slots each
  hp.ctx_all   = carve((size_t)(TT + 1) * CTXS);
  hp.Apre_all  = carve((size_t)(TT + 1) * HS);
  hp.Bpre_all  = carve((size_t)(TT + 1) * HS);
  hp.Apost_all = carve((size_t)(TT + 1) * HS);
  size_t need_floats = off;
  hp.mode = (ws_size / 4 >= need_floats) ? 1 : 0;
  if (!hp.mode) {
    // fresh arrays unused; point them somewhere valid
    hp.ctx_all = hp.ctx0; hp.Apre_all = hp.Apre0;
    hp.Bpre_all = hp.Bpre0; hp.Apost_all = hp.Apost0;
  }

  init_kernel<<<(nstate + 255) / 256, 256, 0, stream>>>(w + state_begin, nstate);
  prenet_kernel<<<TT * BB, 256, 0, stream>>>(hp.tmels, W1, b1, W2, b2, hp.P_all);
  memproj_kernel<<<BB * SS, 128, 0, stream>>>(hp.emb, Wmem, hp.memproj);
  decoder_persistent<<<NBLK, 256, 0, stream>>>(hp);

  (void)in_sizes; (void)n_in; (void)out_size;
}